// Round 7
// baseline (200.052 us; speedup 1.0000x reference)
//
#include <hip/hip_runtime.h>

#define B_ 2
#define C_ 256
#define H_ 56
#define W_ 56
#define N_ 64
#define M_ 8
#define P_ 7
#define R_ (N_ + N_*M_)          // 576 rois per image
#define BR_ (B_*R_)              // 1152
#define WROW_ 8                  // padded weight-row stride (7 used + 1 pad)
#define JPN_ 17                  // j=0: box whole; j>=1: ctx roi (j-1)/2, x-half (j-1)&1

// ---- workspace layout (float-element offsets) ----
#define F_FMT  0
#define N_FMT  (B_*H_*W_*C_)                 // channel-last feature map
#define F_WYD  (F_FMT + N_FMT)
#define N_WYD  (BR_*H_*WROW_)                // dense y-weights [y][py], stride 8
#define F_AXD  (F_WYD + N_WYD)
#define N_AXD  (BR_*W_*WROW_)                // dense x-weights [x][px] (ctx pre-scaled 1/M)
#define E_XLO  (F_AXD + N_AXD)               // int region
#define E_XHI  (E_XLO + BR_)
#define E_YLO  (E_XHI + BR_)
#define E_YHI  (E_YLO + BR_)
#define WS_ELEMS (E_YHI + BR_)

// fused prep kernel block ranges
#define PREP_T 224                           // transpose: B*H*2 blocks (x-halves)
#define PREP_N (PREP_T + 32)                 // weights: 8192 threads

// ---------------------------------------------------------------------------
// k_prep: two jobs in one dispatch.
//   [0,224):   fm[b][c][y][x] -> fmt[b][y][x][c]   (one x-half per block)
//   [224,256): per-(br,p) dense axis weights (verified math since R5)
__global__ __launch_bounds__(256) void k_prep(const float* __restrict__ fm,
                                              const float* __restrict__ boxes,
                                              const float* __restrict__ gt,
                                              float* __restrict__ ws_f) {
    int bid = blockIdx.x;
    int tid = (int)threadIdx.x;

    if (bid < PREP_T) {                      // ---- transpose ----
        int xh  = bid & 1;
        int y   = (bid >> 1) % H_;
        int b   = bid / (2 * H_);
        int c   = tid;                       // all 256 channels
        int x0  = xh * (W_ / 2);
        const float4* src = (const float4*)(fm + (((size_t)b * C_ + c) * H_ + y) * W_ + x0);
        float* dst = ws_f + F_FMT + (((size_t)b * H_ + y) * W_ + x0) * (size_t)C_ + c;
#pragma unroll
        for (int x4 = 0; x4 < W_ / 8; ++x4) {   // 7 float4 = 28 columns
            float4 v = src[x4];
            dst[(x4 * 4 + 0) * C_] = v.x;
            dst[(x4 * 4 + 1) * C_] = v.y;
            dst[(x4 * 4 + 2) * C_] = v.z;
            dst[(x4 * 4 + 3) * C_] = v.w;
        }
        return;
    }

    {                                        // ---- weights ----
        int t = (bid - PREP_T) * 256 + tid;
        if (t >= BR_ * P_) return;
        int p  = t % P_;
        int br = t / P_;
        int r  = br % R_;
        int b  = br / R_;
        int* ip = (int*)ws_f;

        float x1, y1, x2, y2;
        if (r < N_) {
            const float* bp = boxes + ((size_t)b * N_ + r) * 4;
            x1 = bp[0]; y1 = bp[1]; x2 = bp[2]; y2 = bp[3];
        } else {
            int q = r - N_;
            int n = q / M_, m = q % M_;
            const float* bp = boxes + ((size_t)b * N_ + n) * 4;
            const float* gp = gt + ((size_t)b * M_ + m) * 4;
            x1 = fminf(bp[0], gp[0]); y1 = fminf(bp[1], gp[1]);
            x2 = fmaxf(bp[2], gp[2]); y2 = fmaxf(bp[3], gp[3]);
        }
        float rw = fmaxf(x2 - x1, 1.0f);
        float rh = fmaxf(y2 - y1, 1.0f);

        {   // y axis, dense column p
            float bin = rh / 7.0f;
            float gf  = ceilf(bin);
            int   g   = (int)gf;
            float ivg = 1.0f / gf;
            float start = y1 + (float)p * bin;
            float* wcol = ws_f + F_WYD + (size_t)br * (H_ * WROW_) + p;
            for (int y = 0; y < H_; ++y) wcol[y * WROW_] = 0.0f;
            for (int s = 0; s < g; ++s) {
                float coord = start + ((float)s + 0.5f) * bin * ivg;
                if (coord < -1.0f || coord > (float)H_) continue;
                float cc = fmaxf(coord, 0.0f);
                int low = (int)floorf(cc);
                int high; float l;
                if (low >= H_ - 1) { low = H_ - 1; high = H_ - 1; l = 0.0f; }
                else               { high = low + 1; l = cc - (float)low; }
                wcol[low  * WROW_] += (1.0f - l) * ivg;
                wcol[high * WROW_] += l * ivg;
            }
        }
        {   // x axis, dense column p, ctx 1/M folded in
            float bin = rw / 7.0f;
            float gf  = ceilf(bin);
            int   g   = (int)gf;
            float ivg = 1.0f / gf;
            float fs  = (r < N_) ? ivg : ivg * (1.0f / (float)M_);
            float start = x1 + (float)p * bin;
            float* acol = ws_f + F_AXD + (size_t)br * (W_ * WROW_) + p;
            for (int x = 0; x < W_; ++x) acol[x * WROW_] = 0.0f;
            for (int s = 0; s < g; ++s) {
                float coord = start + ((float)s + 0.5f) * bin * ivg;
                if (coord < -1.0f || coord > (float)W_) continue;
                float cc = fmaxf(coord, 0.0f);
                int low = (int)floorf(cc);
                int high; float l;
                if (low >= W_ - 1) { low = W_ - 1; high = W_ - 1; l = 0.0f; }
                else               { high = low + 1; l = cc - (float)low; }
                acol[low  * WROW_] += (1.0f - l) * fs;
                acol[high * WROW_] += l * fs;
            }
            if (p == 0) {
                ip[E_XLO + br] = min(max((int)floorf(fmaxf(x1, 0.0f)), 0), W_ - 1);
                ip[E_XHI + br] = min(max((int)floorf(x1 + rw) + 1, 0), W_ - 1) + 1;
                ip[E_YLO + br] = min(max((int)floorf(fmaxf(y1, 0.0f)), 0), H_ - 1);
                ip[E_YHI + br] = min(max((int)floorf(y1 + rh) + 1, 0), H_ - 1) + 1;
            }
        }
    }
}

// ---------------------------------------------------------------------------
// k_main: block = (b, n, j); j=0 box whole, j>=1 ctx roi (j-1)/2 x-half
// (j-1)&1 -> near-uniform block durations, grid 2176 (~8 resident blocks/CU).
// 256 thr = 4 waves = 4 channel groups. Inner loop: x-quad x y-pair (R6,
// proven): 8 independent loads feed 56 FMAs; weights via wave-uniform s_load.
// Epilogue: LDS-transpose (4 rounds) + coalesced atomicAdd DIRECTLY into
// d_out (zeroed by memset) -> no outS staging, no k_final.
__global__ __launch_bounds__(256, 4) void k_main(const float* __restrict__ ws_f,
                                                 float* __restrict__ out) {
    __shared__ float lds_red[64 * 49];   // 12,544 B
    const int* ip = (const int*)ws_f;
    int bid = blockIdx.x;
    int j   = bid % JPN_;
    int n   = (bid / JPN_) & (N_ - 1);
    int b   = bid / (JPN_ * N_);
    int tid  = (int)threadIdx.x;
    int lane = tid & 63;
    int rg   = tid >> 6;
    int c    = rg * 64 + lane;

    int r, h;
    if (j == 0) { r = n; h = -1; }
    else        { int m = (j - 1) >> 1; h = (j - 1) & 1; r = N_ + n * M_ + m; }
    int br = b * R_ + r;

    int xlo = ip[E_XLO + br];
    int xhi = ip[E_XHI + br];
    int ylo = ip[E_YLO + br];
    int yhi = ip[E_YHI + br];
    int xs, xe;
    if (h < 0) { xs = xlo; xe = xhi; }
    else {
        int cw = (xhi - xlo + 1) >> 1;
        xs = xlo + h * cw;
        xe = min(xs + cw, xhi);
    }
    if (xs >= xe) return;                // block-uniform -> safe w.r.t. barriers

    const float* wyd  = ws_f + F_WYD + (size_t)br * (H_ * WROW_);
    const float* axd  = ws_f + F_AXD + (size_t)br * (W_ * WROW_);
    const float* fmtb = ws_f + F_FMT + (size_t)b * (H_ * W_ * C_);

    float acc[49];
#pragma unroll
    for (int q = 0; q < 49; ++q) acc[q] = 0.0f;

    for (int x = xs; x < xe; x += 4) {
        float cs[4][P_];
#pragma unroll
        for (int i = 0; i < 4; ++i)
#pragma unroll
            for (int py = 0; py < P_; ++py) cs[i][py] = 0.0f;

        // over-read x+1..x+3 / y+1 past roi edge is harmless: addresses stay
        // inside d_ws; garbage columns never enter acc (x-stage gated on xe).
        const float* col = fmtb + ((size_t)(ylo * W_ + x)) * C_ + c;
        int y = ylo;
        for (; y + 2 <= yhi; y += 2) {
            float a0 = col[0];
            float a1 = col[C_];
            float a2 = col[2 * C_];
            float a3 = col[3 * C_];
            float b0 = col[W_ * C_];
            float b1 = col[W_ * C_ + C_];
            float b2 = col[W_ * C_ + 2 * C_];
            float b3 = col[W_ * C_ + 3 * C_];
            const float* w0 = wyd + y * WROW_;        // wave-uniform -> s_load
            const float* w1 = w0 + WROW_;
#pragma unroll
            for (int py = 0; py < P_; ++py) {
                float u0 = w0[py], u1 = w1[py];
                cs[0][py] = fmaf(u1, b0, fmaf(u0, a0, cs[0][py]));
                cs[1][py] = fmaf(u1, b1, fmaf(u0, a1, cs[1][py]));
                cs[2][py] = fmaf(u1, b2, fmaf(u0, a2, cs[2][py]));
                cs[3][py] = fmaf(u1, b3, fmaf(u0, a3, cs[3][py]));
            }
            col += 2 * W_ * C_;
        }
        if (y < yhi) {                                // odd tail row
            float a0 = col[0];
            float a1 = col[C_];
            float a2 = col[2 * C_];
            float a3 = col[3 * C_];
            const float* w0 = wyd + y * WROW_;
#pragma unroll
            for (int py = 0; py < P_; ++py) {
                float u0 = w0[py];
                cs[0][py] = fmaf(u0, a0, cs[0][py]);
                cs[1][py] = fmaf(u0, a1, cs[1][py]);
                cs[2][py] = fmaf(u0, a2, cs[2][py]);
                cs[3][py] = fmaf(u0, a3, cs[3][py]);
            }
        }

        const float* ar = axd + x * WROW_;            // wave-uniform
#pragma unroll
        for (int i = 0; i < 4; ++i) {
            if (x + i < xe) {                         // wave-uniform branch
#pragma unroll
                for (int px = 0; px < P_; ++px) {
                    float w = ar[i * WROW_ + px];
                    if (w != 0.0f) {
#pragma unroll
                        for (int py = 0; py < P_; ++py)
                            acc[py * P_ + px] = fmaf(w, cs[i][py], acc[py * P_ + px]);
                    }
                }
            }
        }
    }

    // ---- epilogue: 4 rounds through lds_red, coalesced atomics into out ----
    float* outb = out + ((size_t)b * N_ + n) * (C_ * 49);
#pragma unroll
    for (int w = 0; w < 4; ++w) {
        if (rg == w) {
#pragma unroll
            for (int q = 0; q < 49; ++q)
                lds_red[lane * 49 + q] = acc[q];      // 49 odd -> conflict-free
        }
        __syncthreads();
        float* outp = outb + w * 64 * 49;
        for (int e = tid; e < 64 * 49; e += 256)
            atomicAdd(&outp[e], lds_red[e]);
        __syncthreads();
    }
}

// ---------------------------------------------------------------------------
extern "C" void kernel_launch(void* const* d_in, const int* in_sizes, int n_in,
                              void* d_out, int out_size, void* d_ws, size_t ws_size,
                              hipStream_t stream) {
    const float* fm    = (const float*)d_in[0];
    const float* boxes = (const float*)d_in[1];
    const float* gt    = (const float*)d_in[2];
    float* ws_f = (float*)d_ws;
    float* out  = (float*)d_out;

    hipMemsetAsync(out, 0, (size_t)out_size * sizeof(float), stream);
    k_prep<<<PREP_N, 256, 0, stream>>>(fm, boxes, gt, ws_f);
    k_main<<<B_ * N_ * JPN_, 256, 0, stream>>>(ws_f, out);
}

// Round 8
// 185.975 us; speedup vs baseline: 1.0757x; 1.0757x over previous
//
#include <hip/hip_runtime.h>

#define B_ 2
#define C_ 256
#define H_ 56
#define W_ 56
#define N_ 64
#define M_ 8
#define P_ 7
#define R_ (N_ + N_*M_)          // 576 rois per image
#define BR_ (B_*R_)              // 1152
#define SCTX_ 4                  // column chunks per ctx roi (box roi = whole)
#define JPN_ (1 + (M_)*SCTX_)    // 33 chunk-jobs per (b,n); x2 py-halves = 66 blocks
#define WROW_ 8                  // padded weight-row stride (7 used + col 7 = zero pad)

// ---- workspace layout (float-element offsets) ----
#define F_FMT  0
#define N_FMT  (B_*H_*W_*C_)                 // channel-last feature map
#define F_WYD  (F_FMT + N_FMT)
#define N_WYD  (BR_*H_*WROW_)                // dense y-weights [y][py], stride 8, col7=0
#define F_AXD  (F_WYD + N_WYD)
#define N_AXD  (BR_*W_*WROW_)                // dense x-weights [x][px] (ctx pre-scaled 1/M)
#define F_OUTS (F_AXD + N_AXD)
#define N_OUTS (B_*N_*49*C_)                 // staging out [b][n][py][px][c]
#define E_XLO  (F_OUTS + N_OUTS)             // int region
#define E_XHI  (E_XLO + BR_)
#define E_YLO  (E_XHI + BR_)
#define E_YHI  (E_YLO + BR_)
#define WS_ELEMS (E_YHI + BR_)               // ~17 MB total

// fused prep kernel block ranges (R6-proven)
#define PREP_T 112                           // transpose: B*H blocks
#define PREP_W (PREP_T + 32)                 // weights: 8192 threads
#define PREP_Z (PREP_W + 784)                // zero outS: 784*2048 floats

// ---------------------------------------------------------------------------
// k_prep: three jobs in one dispatch.
//   [0,112):   fm[b][c][y][x] -> fmt[b][y][x][c]
//   [112,144): per-(br,p) dense axis weights (+ zero wy pad col 7)
//   [144,928): zero outS
__global__ __launch_bounds__(256) void k_prep(const float* __restrict__ fm,
                                              const float* __restrict__ boxes,
                                              const float* __restrict__ gt,
                                              float* __restrict__ ws_f) {
    int bid = blockIdx.x;
    int tid = (int)threadIdx.x;

    if (bid < PREP_T) {                      // ---- transpose ----
        int y = bid % H_, b = bid / H_;
        int c = tid;                         // all 256 channels
        const float4* src = (const float4*)(fm + (((size_t)b * C_ + c) * H_ + y) * W_);
        float* dst = ws_f + F_FMT + ((size_t)b * H_ + y) * (size_t)(W_ * C_) + c;
#pragma unroll
        for (int x4 = 0; x4 < W_ / 4; ++x4) {
            float4 v = src[x4];
            dst[(x4 * 4 + 0) * C_] = v.x;
            dst[(x4 * 4 + 1) * C_] = v.y;
            dst[(x4 * 4 + 2) * C_] = v.z;
            dst[(x4 * 4 + 3) * C_] = v.w;
        }
        return;
    }

    if (bid < PREP_W) {                      // ---- weights ----
        int t = (bid - PREP_T) * 256 + tid;
        if (t >= BR_ * P_) return;
        int p  = t % P_;
        int br = t / P_;
        int r  = br % R_;
        int b  = br / R_;
        int* ip = (int*)ws_f;

        float x1, y1, x2, y2;
        if (r < N_) {
            const float* bp = boxes + ((size_t)b * N_ + r) * 4;
            x1 = bp[0]; y1 = bp[1]; x2 = bp[2]; y2 = bp[3];
        } else {
            int q = r - N_;
            int n = q / M_, m = q % M_;
            const float* bp = boxes + ((size_t)b * N_ + n) * 4;
            const float* gp = gt + ((size_t)b * M_ + m) * 4;
            x1 = fminf(bp[0], gp[0]); y1 = fminf(bp[1], gp[1]);
            x2 = fmaxf(bp[2], gp[2]); y2 = fmaxf(bp[3], gp[3]);
        }
        float rw = fmaxf(x2 - x1, 1.0f);
        float rh = fmaxf(y2 - y1, 1.0f);

        {   // y axis, dense column p (and zero pad col 7 once per roi)
            float bin = rh / 7.0f;
            float gf  = ceilf(bin);
            int   g   = (int)gf;
            float ivg = 1.0f / gf;
            float start = y1 + (float)p * bin;
            float* wcol = ws_f + F_WYD + (size_t)br * (H_ * WROW_) + p;
            for (int y = 0; y < H_; ++y) wcol[y * WROW_] = 0.0f;
            if (p == 0) {                    // pad column: read by py-half 1
                float* pc = ws_f + F_WYD + (size_t)br * (H_ * WROW_) + 7;
                for (int y = 0; y < H_; ++y) pc[y * WROW_] = 0.0f;
            }
            for (int s = 0; s < g; ++s) {
                float coord = start + ((float)s + 0.5f) * bin * ivg;
                if (coord < -1.0f || coord > (float)H_) continue;
                float cc = fmaxf(coord, 0.0f);
                int low = (int)floorf(cc);
                int high; float l;
                if (low >= H_ - 1) { low = H_ - 1; high = H_ - 1; l = 0.0f; }
                else               { high = low + 1; l = cc - (float)low; }
                wcol[low  * WROW_] += (1.0f - l) * ivg;
                wcol[high * WROW_] += l * ivg;
            }
        }
        {   // x axis, dense column p, ctx 1/M folded in
            float bin = rw / 7.0f;
            float gf  = ceilf(bin);
            int   g   = (int)gf;
            float ivg = 1.0f / gf;
            float fs  = (r < N_) ? ivg : ivg * (1.0f / (float)M_);
            float start = x1 + (float)p * bin;
            float* acol = ws_f + F_AXD + (size_t)br * (W_ * WROW_) + p;
            for (int x = 0; x < W_; ++x) acol[x * WROW_] = 0.0f;
            for (int s = 0; s < g; ++s) {
                float coord = start + ((float)s + 0.5f) * bin * ivg;
                if (coord < -1.0f || coord > (float)W_) continue;
                float cc = fmaxf(coord, 0.0f);
                int low = (int)floorf(cc);
                int high; float l;
                if (low >= W_ - 1) { low = W_ - 1; high = W_ - 1; l = 0.0f; }
                else               { high = low + 1; l = cc - (float)low; }
                acol[low  * WROW_] += (1.0f - l) * fs;
                acol[high * WROW_] += l * fs;
            }
            if (p == 0) {
                ip[E_XLO + br] = min(max((int)floorf(fmaxf(x1, 0.0f)), 0), W_ - 1);
                ip[E_XHI + br] = min(max((int)floorf(x1 + rw) + 1, 0), W_ - 1) + 1;
                ip[E_YLO + br] = min(max((int)floorf(fmaxf(y1, 0.0f)), 0), H_ - 1);
                ip[E_YHI + br] = min(max((int)floorf(y1 + rh) + 1, 0), H_ - 1) + 1;
            }
        }
        return;
    }

    {                                        // ---- zero outS ----
        int t = (bid - PREP_W) * 256 + tid;  // < 200,704
        float4 z = {0.0f, 0.0f, 0.0f, 0.0f};
        float4* dst = (float4*)(ws_f + F_OUTS);
        dst[t * 2]     = z;
        dst[t * 2 + 1] = z;
    }
}

// ---------------------------------------------------------------------------
// k_main: block = (b, n, chunk j, py-half ph). ph=0 -> py 0..3, ph=1 ->
// py 4..6 + zero-pad row 7 (uniform unrolled code, pad weights = 0).
// Register budget: cs[4][4]=16 + acc[28] + 8 vals ~= 75 unified regs ->
// 6 waves/SIMD residency cap (R6's cs[4][7]+acc[49] ~= 104 -> only 4).
// Inner loop: x-quad x y-pair, 8 independent loads feed 32 FMAs; weights via
// wave-uniform loads. No LDS, no barriers. Epilogue: live-px coalesced
// atomics into outS [py][px][c], disjoint py rows per half.
__global__ __launch_bounds__(256, 5) void k_main(const float* __restrict__ ws_f,
                                                 float* __restrict__ outs) {
    const int* ip = (const int*)ws_f;
    int bid  = blockIdx.x;
    int ph   = bid & 1;
    int rest = bid >> 1;
    int j    = rest % JPN_;
    int n    = (rest / JPN_) & (N_ - 1);
    int b    = rest / (JPN_ * N_);
    int k, s;
    if (j == 0) { k = 0; s = 0; }
    else        { k = 1 + ((j - 1) >> 2); s = (j - 1) & 3; }
    int tid  = (int)threadIdx.x;
    int lane = tid & 63;
    int rg   = tid >> 6;
    int c    = rg * 64 + lane;
    int py_base = ph << 2;                   // 0 or 4

    int r  = (k == 0) ? n : (N_ + n * M_ + (k - 1));
    int br = b * R_ + r;

    int xlo = ip[E_XLO + br];
    int xhi = ip[E_XHI + br];
    int ylo = ip[E_YLO + br];
    int yhi = ip[E_YHI + br];
    int xs, xe;
    if (k == 0) { xs = xlo; xe = xhi; }
    else {
        int cw = (xhi - xlo + SCTX_ - 1) >> 2;
        xs = xlo + s * cw;
        xe = min(xs + cw, xhi);
    }
    if (xs >= xe) return;

    const float* wydb = ws_f + F_WYD + (size_t)br * (H_ * WROW_) + py_base;
    const float* axd  = ws_f + F_AXD + (size_t)br * (W_ * WROW_);
    const float* fmtb = ws_f + F_FMT + (size_t)b * (H_ * W_ * C_);

    float acc[4 * P_];                       // [pyL][px], pyL = py - py_base
#pragma unroll
    for (int q = 0; q < 4 * P_; ++q) acc[q] = 0.0f;
    int live = 0;

    for (int x = xs; x < xe; x += 4) {
        float cs[4][4];                      // [col][pyL]
#pragma unroll
        for (int i = 0; i < 4; ++i)
#pragma unroll
            for (int t = 0; t < 4; ++t) cs[i][t] = 0.0f;

        // over-read x+1..x+3 / y+1 past roi edge is harmless: addresses stay
        // inside d_ws; garbage columns never enter acc (gated on xe).
        const float* col = fmtb + ((size_t)(ylo * W_ + x)) * C_ + c;
        int y = ylo;
        for (; y + 2 <= yhi; y += 2) {
            float a0 = col[0];
            float a1 = col[C_];
            float a2 = col[2 * C_];
            float a3 = col[3 * C_];
            float b0 = col[W_ * C_];
            float b1 = col[W_ * C_ + C_];
            float b2 = col[W_ * C_ + 2 * C_];
            float b3 = col[W_ * C_ + 3 * C_];
            const float* w0 = wydb + y * WROW_;       // wave-uniform
            const float* w1 = w0 + WROW_;
#pragma unroll
            for (int t = 0; t < 4; ++t) {
                float u0 = w0[t], u1 = w1[t];
                cs[0][t] = fmaf(u1, b0, fmaf(u0, a0, cs[0][t]));
                cs[1][t] = fmaf(u1, b1, fmaf(u0, a1, cs[1][t]));
                cs[2][t] = fmaf(u1, b2, fmaf(u0, a2, cs[2][t]));
                cs[3][t] = fmaf(u1, b3, fmaf(u0, a3, cs[3][t]));
            }
            col += 2 * W_ * C_;
        }
        if (y < yhi) {                                // odd tail row
            float a0 = col[0];
            float a1 = col[C_];
            float a2 = col[2 * C_];
            float a3 = col[3 * C_];
            const float* w0 = wydb + y * WROW_;
#pragma unroll
            for (int t = 0; t < 4; ++t) {
                float u0 = w0[t];
                cs[0][t] = fmaf(u0, a0, cs[0][t]);
                cs[1][t] = fmaf(u0, a1, cs[1][t]);
                cs[2][t] = fmaf(u0, a2, cs[2][t]);
                cs[3][t] = fmaf(u0, a3, cs[3][t]);
            }
        }

        const float* ar = axd + x * WROW_;            // wave-uniform
#pragma unroll
        for (int i = 0; i < 4; ++i) {
            if (x + i < xe) {                         // wave-uniform branch
#pragma unroll
                for (int px = 0; px < P_; ++px) {
                    float w = ar[i * WROW_ + px];
                    if (w != 0.0f) {
                        live |= 1 << px;
#pragma unroll
                        for (int t = 0; t < 4; ++t)
                            acc[t * P_ + px] = fmaf(w, cs[i][t], acc[t * P_ + px]);
                    }
                }
            }
        }
    }

    // ---- epilogue: coalesced wave-atomics, live px, this half's py rows ----
    float* os = outs + ((size_t)b * N_ + n) * (49 * C_) + c;
#pragma unroll
    for (int px = 0; px < P_; ++px) {
        if (live & (1 << px)) {
#pragma unroll
            for (int t = 0; t < 4; ++t) {
                int py = py_base + t;
                if (py < P_)                          // skips pad row (ph=1,t=3)
                    atomicAdd(os + (py * P_ + px) * C_, acc[t * P_ + px]);
            }
        }
    }
}

// ---------------------------------------------------------------------------
// k_final: outS [b][n][py][px][c] -> out [b][n][c][py][px] via padded LDS.
__global__ __launch_bounds__(256) void k_final(const float* __restrict__ outs,
                                               float* __restrict__ out) {
    __shared__ float t[49 * 257];        // pad 257: conflict-free transpose read
    int bn  = blockIdx.x;                // 0..B*N-1
    int tid = (int)threadIdx.x;
    const float* src = outs + (size_t)bn * (49 * C_);
    for (int e = tid; e < 49 * C_; e += 256) {
        int q = e >> 8, c = e & 255;
        t[q * 257 + c] = src[e];         // coalesced read
    }
    __syncthreads();
    float* dst = out + (size_t)bn * (C_ * 49);
    for (int e = tid; e < C_ * 49; e += 256) {
        int c = e / 49, q = e % 49;
        dst[e] = t[q * 257 + c];         // coalesced write
    }
}

// ---------------------------------------------------------------------------
extern "C" void kernel_launch(void* const* d_in, const int* in_sizes, int n_in,
                              void* d_out, int out_size, void* d_ws, size_t ws_size,
                              hipStream_t stream) {
    const float* fm    = (const float*)d_in[0];
    const float* boxes = (const float*)d_in[1];
    const float* gt    = (const float*)d_in[2];
    float* ws_f = (float*)d_ws;
    float* out  = (float*)d_out;
    float* outs = ws_f + F_OUTS;

    k_prep<<<PREP_Z, 256, 0, stream>>>(fm, boxes, gt, ws_f);
    k_main<<<B_ * N_ * JPN_ * 2, 256, 0, stream>>>(ws_f, outs);
    k_final<<<B_ * N_, 256, 0, stream>>>(outs, out);
}

// Round 9
// 181.799 us; speedup vs baseline: 1.1004x; 1.0230x over previous
//
#include <hip/hip_runtime.h>

#define B_ 2
#define C_ 256
#define H_ 56
#define W_ 56
#define N_ 64
#define M_ 8
#define P_ 7
#define R_ (N_ + N_*M_)          // 576 rois per image
#define BR_ (B_*R_)              // 1152
#define WROW_ 8                  // padded weight-row stride (7 used + col7 = 0)
#define JPN_ 65                  // j=0 box whole; j>=1: ctx m=(j-1)/8, qx, qy

// ---- workspace layout (float-element offsets) ----
#define F_FMT  0
#define N_FMT  (B_*H_*W_*C_)                 // channel-last feature map (32B-aligned rows)
#define F_WYD  (F_FMT + N_FMT)
#define N_WYD  (BR_*H_*WROW_)                // dense y-weights [y][py], col7=0
#define F_AXD  (F_WYD + N_WYD)
#define N_AXD  (BR_*W_*WROW_)                // dense x-weights [x][px] (ctx pre-scaled 1/M), col7=0
#define F_OUTS (F_AXD + N_AXD)
#define N_OUTS (B_*N_*49*C_)                 // staging out [b][n][py][px][c]
#define E_XLO  (F_OUTS + N_OUTS)             // int region
#define E_XHI  (E_XLO + BR_)
#define E_YLO  (E_XHI + BR_)
#define E_YHI  (E_YLO + BR_)
#define E_PYB  (E_YHI + BR_)                 // per-(br,py) first nonzero row [BR][8]
#define E_PYE  (E_PYB + BR_*8)               // per-(br,py) last nonzero row+1 [BR][8]
#define WS_ELEMS (E_PYE + BR_*8)             // ~17 MB total

// fused prep kernel block ranges
#define PREP_T 112                           // transpose: B*H blocks
#define PREP_W (PREP_T + 32)                 // weights: 8192 threads
#define PREP_Z (PREP_W + 784)                // zero outS: 784*2048 floats

// ---------------------------------------------------------------------------
// k_prep: three jobs in one dispatch.
__global__ __launch_bounds__(256) void k_prep(const float* __restrict__ fm,
                                              const float* __restrict__ boxes,
                                              const float* __restrict__ gt,
                                              float* __restrict__ ws_f) {
    int bid = blockIdx.x;
    int tid = (int)threadIdx.x;

    if (bid < PREP_T) {                      // ---- transpose ----
        int y = bid % H_, b = bid / H_;
        int c = tid;                         // all 256 channels
        const float4* src = (const float4*)(fm + (((size_t)b * C_ + c) * H_ + y) * W_);
        float* dst = ws_f + F_FMT + ((size_t)b * H_ + y) * (size_t)(W_ * C_) + c;
#pragma unroll
        for (int x4 = 0; x4 < W_ / 4; ++x4) {
            float4 v = src[x4];
            dst[(x4 * 4 + 0) * C_] = v.x;
            dst[(x4 * 4 + 1) * C_] = v.y;
            dst[(x4 * 4 + 2) * C_] = v.z;
            dst[(x4 * 4 + 3) * C_] = v.w;
        }
        return;
    }

    if (bid < PREP_W) {                      // ---- weights ----
        int t = (bid - PREP_T) * 256 + tid;
        if (t >= BR_ * P_) return;
        int p  = t % P_;
        int br = t / P_;
        int r  = br % R_;
        int b  = br / R_;
        int* ip = (int*)ws_f;

        float x1, y1, x2, y2;
        if (r < N_) {
            const float* bp = boxes + ((size_t)b * N_ + r) * 4;
            x1 = bp[0]; y1 = bp[1]; x2 = bp[2]; y2 = bp[3];
        } else {
            int q = r - N_;
            int n = q / M_, m = q % M_;
            const float* bp = boxes + ((size_t)b * N_ + n) * 4;
            const float* gp = gt + ((size_t)b * M_ + m) * 4;
            x1 = fminf(bp[0], gp[0]); y1 = fminf(bp[1], gp[1]);
            x2 = fmaxf(bp[2], gp[2]); y2 = fmaxf(bp[3], gp[3]);
        }
        float rw = fmaxf(x2 - x1, 1.0f);
        float rh = fmaxf(y2 - y1, 1.0f);

        {   // y axis, dense column p + nonzero-row window + zero pad col 7
            float bin = rh / 7.0f;
            float gf  = ceilf(bin);
            int   g   = (int)gf;
            float ivg = 1.0f / gf;
            float start = y1 + (float)p * bin;
            float* wcol = ws_f + F_WYD + (size_t)br * (H_ * WROW_) + p;
            for (int y = 0; y < H_; ++y) wcol[y * WROW_] = 0.0f;
            if (p == 0) {
                float* pc = ws_f + F_WYD + (size_t)br * (H_ * WROW_) + 7;
                for (int y = 0; y < H_; ++y) pc[y * WROW_] = 0.0f;
            }
            int beg = H_, end = 0;
            for (int s = 0; s < g; ++s) {
                float coord = start + ((float)s + 0.5f) * bin * ivg;
                if (coord < -1.0f || coord > (float)H_) continue;
                float cc = fmaxf(coord, 0.0f);
                int low = (int)floorf(cc);
                int high; float l;
                if (low >= H_ - 1) { low = H_ - 1; high = H_ - 1; l = 0.0f; }
                else               { high = low + 1; l = cc - (float)low; }
                wcol[low  * WROW_] += (1.0f - l) * ivg;
                wcol[high * WROW_] += l * ivg;
                beg = min(beg, low);
                end = max(end, high + 1);
            }
            if (beg >= end) { beg = 0; end = 0; }
            ip[E_PYB + br * 8 + p] = beg;
            ip[E_PYE + br * 8 + p] = end;
        }
        {   // x axis, dense column p, ctx 1/M folded in, zero pad col 7
            float bin = rw / 7.0f;
            float gf  = ceilf(bin);
            int   g   = (int)gf;
            float ivg = 1.0f / gf;
            float fs  = (r < N_) ? ivg : ivg * (1.0f / (float)M_);
            float start = x1 + (float)p * bin;
            float* acol = ws_f + F_AXD + (size_t)br * (W_ * WROW_) + p;
            for (int x = 0; x < W_; ++x) acol[x * WROW_] = 0.0f;
            if (p == 0) {
                float* pc = ws_f + F_AXD + (size_t)br * (W_ * WROW_) + 7;
                for (int x = 0; x < W_; ++x) pc[x * WROW_] = 0.0f;
            }
            for (int s = 0; s < g; ++s) {
                float coord = start + ((float)s + 0.5f) * bin * ivg;
                if (coord < -1.0f || coord > (float)W_) continue;
                float cc = fmaxf(coord, 0.0f);
                int low = (int)floorf(cc);
                int high; float l;
                if (low >= W_ - 1) { low = W_ - 1; high = W_ - 1; l = 0.0f; }
                else               { high = low + 1; l = cc - (float)low; }
                acol[low  * WROW_] += (1.0f - l) * fs;
                acol[high * WROW_] += l * fs;
            }
            if (p == 0) {
                ip[E_XLO + br] = min(max((int)floorf(fmaxf(x1, 0.0f)), 0), W_ - 1);
                ip[E_XHI + br] = min(max((int)floorf(x1 + rw) + 1, 0), W_ - 1) + 1;
                ip[E_YLO + br] = min(max((int)floorf(fmaxf(y1, 0.0f)), 0), H_ - 1);
                ip[E_YHI + br] = min(max((int)floorf(y1 + rh) + 1, 0), H_ - 1) + 1;
            }
        }
        return;
    }

    {                                        // ---- zero outS ----
        int t = (bid - PREP_W) * 256 + tid;  // < 200,704
        float4 z = {0.0f, 0.0f, 0.0f, 0.0f};
        float4* dst = (float4*)(ws_f + F_OUTS);
        dst[t * 2]     = z;
        dst[t * 2 + 1] = z;
    }
}

// ---------------------------------------------------------------------------
// k_main: block = (b, n, j). j=0: box roi whole. j>=1: ctx roi m=(j-1)/8,
// x-quarter qx, y-half qy -> 8320 small near-uniform blocks (no y-stage work
// duplication: y rows partition disjointly; only the cheap x-stage runs per
// y-half). 256 thr = 4 waves = 4 channel groups. Inner: x-quad x y-pair,
// 8 independent data loads + 4 float4 weight loads feed 56 FMAs. Epilogue:
// (py-live x px-live) coalesced atomics into outS; py-liveness from stored
// nonzero-row windows (acc rows outside this y-chunk are exactly 0).
__global__ __launch_bounds__(256, 4) void k_main(const float* __restrict__ ws_f,
                                                 float* __restrict__ outs) {
    const int* ip = (const int*)ws_f;
    int bid = blockIdx.x;
    int j   = bid % JPN_;
    int n   = (bid / JPN_) & (N_ - 1);
    int b   = bid / (JPN_ * N_);
    int tid  = (int)threadIdx.x;
    int lane = tid & 63;
    int rg   = tid >> 6;
    int c    = rg * 64 + lane;

    int r, qx, qy;
    if (j == 0) { r = n; qx = -1; qy = 0; }
    else {
        int t = j - 1;
        int m = t >> 3;
        qx = (t >> 1) & 3;
        qy = t & 1;
        r = N_ + n * M_ + m;
    }
    int br = b * R_ + r;

    int xlo = ip[E_XLO + br];
    int xhi = ip[E_XHI + br];
    int ylo = ip[E_YLO + br];
    int yhi = ip[E_YHI + br];
    int xs, xe, ys, ye;
    if (qx < 0) { xs = xlo; xe = xhi; ys = ylo; ye = yhi; }
    else {
        int cw  = (xhi - xlo + 3) >> 2;
        xs = xlo + qx * cw;  xe = min(xs + cw, xhi);
        int rh2 = (yhi - ylo + 1) >> 1;
        ys = ylo + qy * rh2; ye = min(ys + rh2, yhi);
    }
    if (xs >= xe || ys >= ye) return;        // no barriers in kernel -> safe

    const float* wyd  = ws_f + F_WYD + (size_t)br * (H_ * WROW_);
    const float* axd  = ws_f + F_AXD + (size_t)br * (W_ * WROW_);
    const float* fmtb = ws_f + F_FMT + (size_t)b * (H_ * W_ * C_);

    float acc[49];
#pragma unroll
    for (int q = 0; q < 49; ++q) acc[q] = 0.0f;
    int live = 0;

    for (int x = xs; x < xe; x += 4) {
        float cs[4][P_];
#pragma unroll
        for (int i = 0; i < 4; ++i)
#pragma unroll
            for (int py = 0; py < P_; ++py) cs[i][py] = 0.0f;

        // over-read x+1..x+3 / y+1 past roi edge stays inside d_ws; garbage
        // columns never enter acc (x-stage gated on xe).
        const float* col = fmtb + ((size_t)(ys * W_ + x)) * C_ + c;
        int y = ys;
        for (; y + 2 <= ye; y += 2) {
            float d0 = col[0];
            float d1 = col[C_];
            float d2 = col[2 * C_];
            float d3 = col[3 * C_];
            float e0 = col[W_ * C_];
            float e1 = col[W_ * C_ + C_];
            float e2 = col[W_ * C_ + 2 * C_];
            float e3 = col[W_ * C_ + 3 * C_];
            float w0[8], w1[8];
            *(float4*)(&w0[0]) = *(const float4*)(wyd + y * WROW_);
            *(float4*)(&w0[4]) = *(const float4*)(wyd + y * WROW_ + 4);
            *(float4*)(&w1[0]) = *(const float4*)(wyd + (y + 1) * WROW_);
            *(float4*)(&w1[4]) = *(const float4*)(wyd + (y + 1) * WROW_ + 4);
#pragma unroll
            for (int py = 0; py < P_; ++py) {
                float u0 = w0[py], u1 = w1[py];
                cs[0][py] = fmaf(u1, e0, fmaf(u0, d0, cs[0][py]));
                cs[1][py] = fmaf(u1, e1, fmaf(u0, d1, cs[1][py]));
                cs[2][py] = fmaf(u1, e2, fmaf(u0, d2, cs[2][py]));
                cs[3][py] = fmaf(u1, e3, fmaf(u0, d3, cs[3][py]));
            }
            col += 2 * W_ * C_;
        }
        if (y < ye) {                                 // odd tail row
            float d0 = col[0];
            float d1 = col[C_];
            float d2 = col[2 * C_];
            float d3 = col[3 * C_];
            float w0[8];
            *(float4*)(&w0[0]) = *(const float4*)(wyd + y * WROW_);
            *(float4*)(&w0[4]) = *(const float4*)(wyd + y * WROW_ + 4);
#pragma unroll
            for (int py = 0; py < P_; ++py) {
                float u0 = w0[py];
                cs[0][py] = fmaf(u0, d0, cs[0][py]);
                cs[1][py] = fmaf(u0, d1, cs[1][py]);
                cs[2][py] = fmaf(u0, d2, cs[2][py]);
                cs[3][py] = fmaf(u0, d3, cs[3][py]);
            }
        }

#pragma unroll
        for (int i = 0; i < 4; ++i) {
            if (x + i < xe) {                         // wave-uniform branch
                float av[8];
                *(float4*)(&av[0]) = *(const float4*)(axd + (x + i) * WROW_);
                *(float4*)(&av[4]) = *(const float4*)(axd + (x + i) * WROW_ + 4);
#pragma unroll
                for (int px = 0; px < P_; ++px) {
                    float w = av[px];
                    if (w != 0.0f) {
                        live |= 1 << px;
#pragma unroll
                        for (int py = 0; py < P_; ++py)
                            acc[py * P_ + px] = fmaf(w, cs[i][py], acc[py * P_ + px]);
                    }
                }
            }
        }
    }

    // ---- epilogue: (py-live x px-live) coalesced wave-atomics into outS ----
    float* os = outs + ((size_t)b * N_ + n) * (49 * C_) + c;
    const int* pb = ip + E_PYB + br * 8;
    const int* pe = ip + E_PYE + br * 8;
#pragma unroll
    for (int py = 0; py < P_; ++py) {
        if (pb[py] < ye && pe[py] > ys) {             // py window hits chunk
#pragma unroll
            for (int px = 0; px < P_; ++px) {
                if (live & (1 << px))
                    atomicAdd(os + (py * P_ + px) * C_, acc[py * P_ + px]);
            }
        }
    }
}

// ---------------------------------------------------------------------------
// k_final: outS [b][n][py][px][c] -> out [b][n][c][py][px] via padded LDS.
__global__ __launch_bounds__(256) void k_final(const float* __restrict__ outs,
                                               float* __restrict__ out) {
    __shared__ float t[49 * 257];        // pad 257: conflict-free transpose read
    int bn  = blockIdx.x;                // 0..B*N-1
    int tid = (int)threadIdx.x;
    const float* src = outs + (size_t)bn * (49 * C_);
    for (int e = tid; e < 49 * C_; e += 256) {
        int q = e >> 8, c = e & 255;
        t[q * 257 + c] = src[e];         // coalesced read
    }
    __syncthreads();
    float* dst = out + (size_t)bn * (C_ * 49);
    for (int e = tid; e < C_ * 49; e += 256) {
        int c = e / 49, q = e % 49;
        dst[e] = t[q * 257 + c];         // coalesced write
    }
}

// ---------------------------------------------------------------------------
extern "C" void kernel_launch(void* const* d_in, const int* in_sizes, int n_in,
                              void* d_out, int out_size, void* d_ws, size_t ws_size,
                              hipStream_t stream) {
    const float* fm    = (const float*)d_in[0];
    const float* boxes = (const float*)d_in[1];
    const float* gt    = (const float*)d_in[2];
    float* ws_f = (float*)d_ws;
    float* out  = (float*)d_out;
    float* outs = ws_f + F_OUTS;

    k_prep<<<PREP_Z, 256, 0, stream>>>(fm, boxes, gt, ws_f);
    k_main<<<B_ * N_ * JPN_, 256, 0, stream>>>(ws_f, outs);
    k_final<<<B_ * N_, 256, 0, stream>>>(outs, out);
}

// Round 10
// 181.230 us; speedup vs baseline: 1.1039x; 1.0031x over previous
//
#include <hip/hip_runtime.h>

#define B_ 2
#define C_ 256
#define H_ 56
#define W_ 56
#define N_ 64
#define M_ 8
#define P_ 7
#define R_ (N_ + N_*M_)          // 576 rois per image
#define BR_ (B_*R_)              // 1152
#define Y2_ (H_/2)               // 28 y-row pairs
#define SCTX_ 4                  // column chunks per ctx roi (box roi = whole)
#define JPN_ (1 + (M_)*SCTX_)    // 33 jobs per (b,n) -> 4224 blocks (R6-proven)
#define WROW_ 8                  // padded weight-row stride (7 used + col7 = 0)

typedef _Float16 half2v __attribute__((ext_vector_type(2)));

#if __has_builtin(__builtin_amdgcn_fdot2)
#define FDOT2(a, b, c) __builtin_amdgcn_fdot2((a), (b), (c), false)
#else
static __device__ __forceinline__ float FDOT2(half2v a, half2v b, float c) {
    return fmaf((float)a.x, (float)b.x, fmaf((float)a.y, (float)b.y, c));
}
#endif

// ---- workspace layout (dword-element offsets) ----
#define F_FMT3 0
#define N_FMT3 (B_*Y2_*W_*C_)                // 802,816  f16 y-pair-packed fmap [b][y2][x][c]
#define F_WY2  (F_FMT3 + N_FMT3)
#define N_WY2  (BR_*Y2_*WROW_)               // 258,048  half2 y-weights [y2][py], col7=0
#define F_AXD  (F_WY2 + N_WY2)
#define N_AXD  (BR_*W_*WROW_)                // 516,096  fp32 x-weights [x][px] (ctx /M), col7=0
#define F_OUTS (F_AXD + N_AXD)
#define N_OUTS (B_*N_*49*C_)                 // 1,605,632 staging out [b][n][py][px][c]
#define E_XLO  (F_OUTS + N_OUTS)             // int region
#define E_XHI  (E_XLO + BR_)
#define E_YLO  (E_XHI + BR_)
#define E_YHI  (E_YLO + BR_)
#define WS_ELEMS (E_YHI + BR_)               // ~12.7 MB

// fused prep kernel block ranges
#define PREP_T (B_*Y2_)                      // 56: f16 pack-transpose
#define PREP_W (PREP_T + 32)                 // 88: weights (8192 threads)
#define PREP_N (PREP_W + 784)                // 872: zero outS (784*2048 floats)

// ---------------------------------------------------------------------------
// k_prep: three jobs in one dispatch.
//   [0,56):   fm[b][c][y][x] -> fmt3[b][y2][x][c] packed half2(row 2y2, 2y2+1)
//   [56,88):  per-(br,p) dense axis weights: wy packed half2 per y-pair,
//             ax fp32; thread-private accumulation (no global RMW races)
//   [88,872): zero outS
__global__ __launch_bounds__(256) void k_prep(const float* __restrict__ fm,
                                              const float* __restrict__ boxes,
                                              const float* __restrict__ gt,
                                              float* __restrict__ ws_f) {
    int bid = blockIdx.x;
    int tid = (int)threadIdx.x;

    if (bid < PREP_T) {                      // ---- pack-transpose ----
        int y2 = bid % Y2_, b = bid / Y2_;
        int c = tid;                         // all 256 channels
        const float4* r0 = (const float4*)(fm + (((size_t)b * C_ + c) * H_ + 2 * y2) * W_);
        const float4* r1 = (const float4*)(fm + (((size_t)b * C_ + c) * H_ + 2 * y2 + 1) * W_);
        unsigned int* dst = (unsigned int*)ws_f + F_FMT3 +
                            ((size_t)b * Y2_ + y2) * (size_t)(W_ * C_) + c;
#pragma unroll
        for (int x4 = 0; x4 < W_ / 4; ++x4) {
            float4 a = r0[x4];
            float4 bb = r1[x4];
            half2v h0; h0.x = (_Float16)a.x; h0.y = (_Float16)bb.x;
            half2v h1; h1.x = (_Float16)a.y; h1.y = (_Float16)bb.y;
            half2v h2; h2.x = (_Float16)a.z; h2.y = (_Float16)bb.z;
            half2v h3; h3.x = (_Float16)a.w; h3.y = (_Float16)bb.w;
            dst[(x4 * 4 + 0) * C_] = __builtin_bit_cast(unsigned int, h0);
            dst[(x4 * 4 + 1) * C_] = __builtin_bit_cast(unsigned int, h1);
            dst[(x4 * 4 + 2) * C_] = __builtin_bit_cast(unsigned int, h2);
            dst[(x4 * 4 + 3) * C_] = __builtin_bit_cast(unsigned int, h3);
        }
        return;
    }

    if (bid < PREP_W) {                      // ---- weights ----
        int t = (bid - PREP_T) * 256 + tid;
        if (t >= BR_ * P_) return;
        int p  = t % P_;
        int br = t / P_;
        int r  = br % R_;
        int b  = br / R_;
        int* ip = (int*)ws_f;

        float x1, y1, x2, y2;
        if (r < N_) {
            const float* bp = boxes + ((size_t)b * N_ + r) * 4;
            x1 = bp[0]; y1 = bp[1]; x2 = bp[2]; y2 = bp[3];
        } else {
            int q = r - N_;
            int n = q / M_, m = q % M_;
            const float* bp = boxes + ((size_t)b * N_ + n) * 4;
            const float* gp = gt + ((size_t)b * M_ + m) * 4;
            x1 = fminf(bp[0], gp[0]); y1 = fminf(bp[1], gp[1]);
            x2 = fmaxf(bp[2], gp[2]); y2 = fmaxf(bp[3], gp[3]);
        }
        float rw = fmaxf(x2 - x1, 1.0f);
        float rh = fmaxf(y2 - y1, 1.0f);

        {   // y axis, dense column p in private array, then pack half2 pairs
            float wloc[H_];
#pragma unroll
            for (int y = 0; y < H_; ++y) wloc[y] = 0.0f;
            float bin = rh / 7.0f;
            float gf  = ceilf(bin);
            int   g   = (int)gf;
            float ivg = 1.0f / gf;
            float start = y1 + (float)p * bin;
            for (int s = 0; s < g; ++s) {
                float coord = start + ((float)s + 0.5f) * bin * ivg;
                if (coord < -1.0f || coord > (float)H_) continue;
                float cc = fmaxf(coord, 0.0f);
                int low = (int)floorf(cc);
                int high; float l;
                if (low >= H_ - 1) { low = H_ - 1; high = H_ - 1; l = 0.0f; }
                else               { high = low + 1; l = cc - (float)low; }
                wloc[low]  += (1.0f - l) * ivg;
                wloc[high] += l * ivg;
            }
            unsigned int* wrow = (unsigned int*)ws_f + F_WY2 + (size_t)br * (Y2_ * WROW_);
            for (int q2 = 0; q2 < Y2_; ++q2) {
                half2v h; h.x = (_Float16)wloc[2 * q2]; h.y = (_Float16)wloc[2 * q2 + 1];
                wrow[q2 * WROW_ + p] = __builtin_bit_cast(unsigned int, h);
                if (p == 0) wrow[q2 * WROW_ + 7] = 0u;   // pad col
            }
        }
        {   // x axis, dense column p fp32, ctx 1/M folded in
            float aloc[W_];
#pragma unroll
            for (int x = 0; x < W_; ++x) aloc[x] = 0.0f;
            float bin = rw / 7.0f;
            float gf  = ceilf(bin);
            int   g   = (int)gf;
            float ivg = 1.0f / gf;
            float fs  = (r < N_) ? ivg : ivg * (1.0f / (float)M_);
            float start = x1 + (float)p * bin;
            for (int s = 0; s < g; ++s) {
                float coord = start + ((float)s + 0.5f) * bin * ivg;
                if (coord < -1.0f || coord > (float)W_) continue;
                float cc = fmaxf(coord, 0.0f);
                int low = (int)floorf(cc);
                int high; float l;
                if (low >= W_ - 1) { low = W_ - 1; high = W_ - 1; l = 0.0f; }
                else               { high = low + 1; l = cc - (float)low; }
                aloc[low]  += (1.0f - l) * fs;
                aloc[high] += l * fs;
            }
            float* arow = ws_f + F_AXD + (size_t)br * (W_ * WROW_);
            for (int x = 0; x < W_; ++x) {
                arow[x * WROW_ + p] = aloc[x];
                if (p == 0) arow[x * WROW_ + 7] = 0.0f;  // pad col
            }
            if (p == 0) {
                ip[E_XLO + br] = min(max((int)floorf(fmaxf(x1, 0.0f)), 0), W_ - 1);
                ip[E_XHI + br] = min(max((int)floorf(x1 + rw) + 1, 0), W_ - 1) + 1;
                ip[E_YLO + br] = min(max((int)floorf(fmaxf(y1, 0.0f)), 0), H_ - 1);
                ip[E_YHI + br] = min(max((int)floorf(y1 + rh) + 1, 0), H_ - 1) + 1;
            }
        }
        return;
    }

    {                                        // ---- zero outS ----
        int t = (bid - PREP_W) * 256 + tid;  // < 200,704
        float4 z = {0.0f, 0.0f, 0.0f, 0.0f};
        float4* dst = (float4*)(ws_f + F_OUTS);
        dst[t * 2]     = z;
        dst[t * 2 + 1] = z;
    }
}

// ---------------------------------------------------------------------------
// k_main: block = (b, n, j) (R6-proven chunking: j=0 box whole, else ctx roi
// (j-1)/4, x-quarter (j-1)&3). 256 thr = 4 waves = 4 channel groups. Inner
// loop: x-PAIR x y-PAIR via v_dot2_f32_f16: per y2-iter 2 data dwords +
// 2 weight dwordx4 feed 14 dot2 (= 28 FMAs) with fp32 accumulation ->
// y-issue halved vs R6, registers cs[2][7]+acc[49] ~= 90 -> 5 waves/SIMD.
// Epilogue: live-px coalesced atomics into outS [py][px][c].
__global__ __launch_bounds__(256, 4) void k_main(const float* __restrict__ ws_f,
                                                 float* __restrict__ outs) {
    const int* ip = (const int*)ws_f;
    int bid = blockIdx.x;
    int j   = bid % JPN_;
    int n   = (bid / JPN_) & (N_ - 1);
    int b   = bid / (JPN_ * N_);
    int k, s;
    if (j == 0) { k = 0; s = 0; }
    else        { k = 1 + ((j - 1) >> 2); s = (j - 1) & 3; }
    int tid  = (int)threadIdx.x;
    int lane = tid & 63;
    int rg   = tid >> 6;
    int c    = rg * 64 + lane;

    int r  = (k == 0) ? n : (N_ + n * M_ + (k - 1));
    int br = b * R_ + r;

    int xlo = ip[E_XLO + br];
    int xhi = ip[E_XHI + br];
    int ylo = ip[E_YLO + br];
    int yhi = ip[E_YHI + br];
    int xs, xe;
    if (k == 0) { xs = xlo; xe = xhi; }
    else {
        int cw = (xhi - xlo + SCTX_ - 1) >> 2;
        xs = xlo + s * cw;
        xe = min(xs + cw, xhi);
    }
    if (xs >= xe) return;                    // no barriers in kernel -> safe

    int ylo2 = ylo >> 1;                     // pair range covering [ylo,yhi)
    int yhi2 = (yhi + 1) >> 1;               // extra rows have zero weight

    const unsigned int* wy2 = (const unsigned int*)ws_f + F_WY2 + (size_t)br * (Y2_ * WROW_);
    const float*        axd = ws_f + F_AXD + (size_t)br * (W_ * WROW_);
    const unsigned int* f3  = (const unsigned int*)ws_f + F_FMT3 + (size_t)b * (Y2_ * W_ * C_);

    float acc[49];
#pragma unroll
    for (int q = 0; q < 49; ++q) acc[q] = 0.0f;
    int live = 0;

    for (int x = xs; x < xe; x += 2) {
        float cs0[P_], cs1[P_];
#pragma unroll
        for (int py = 0; py < P_; ++py) { cs0[py] = 0.0f; cs1[py] = 0.0f; }

        // x+1 over-read past xe/roi edge is harmless: stays inside d_ws,
        // garbage column never enters acc (x-stage gated on xe).
        const unsigned int* col = f3 + ((size_t)(ylo2 * W_ + x)) * C_ + c;
        for (int y2 = ylo2; y2 < yhi2; ++y2) {
            unsigned int d0 = col[0];
            unsigned int d1 = col[C_];
            const uint4* wr = (const uint4*)(wy2 + y2 * WROW_);
            uint4 wa = wr[0];
            uint4 wb = wr[1];
            half2v v0 = __builtin_bit_cast(half2v, d0);
            half2v v1 = __builtin_bit_cast(half2v, d1);
            half2v w[7];
            w[0] = __builtin_bit_cast(half2v, wa.x);
            w[1] = __builtin_bit_cast(half2v, wa.y);
            w[2] = __builtin_bit_cast(half2v, wa.z);
            w[3] = __builtin_bit_cast(half2v, wa.w);
            w[4] = __builtin_bit_cast(half2v, wb.x);
            w[5] = __builtin_bit_cast(half2v, wb.y);
            w[6] = __builtin_bit_cast(half2v, wb.z);
#pragma unroll
            for (int py = 0; py < P_; ++py) {
                cs0[py] = FDOT2(w[py], v0, cs0[py]);
                cs1[py] = FDOT2(w[py], v1, cs1[py]);
            }
            col += W_ * C_;
        }

        // ---- x-stage (fp32, exact weights) ----
        {
            float av[8];
            *(float4*)(&av[0]) = *(const float4*)(axd + x * WROW_);
            *(float4*)(&av[4]) = *(const float4*)(axd + x * WROW_ + 4);
#pragma unroll
            for (int px = 0; px < P_; ++px) {
                float w = av[px];
                if (w != 0.0f) {                      // wave-uniform branch
                    live |= 1 << px;
#pragma unroll
                    for (int py = 0; py < P_; ++py)
                        acc[py * P_ + px] = fmaf(w, cs0[py], acc[py * P_ + px]);
                }
            }
        }
        if (x + 1 < xe) {
            float av[8];
            *(float4*)(&av[0]) = *(const float4*)(axd + (x + 1) * WROW_);
            *(float4*)(&av[4]) = *(const float4*)(axd + (x + 1) * WROW_ + 4);
#pragma unroll
            for (int px = 0; px < P_; ++px) {
                float w = av[px];
                if (w != 0.0f) {
                    live |= 1 << px;
#pragma unroll
                    for (int py = 0; py < P_; ++py)
                        acc[py * P_ + px] = fmaf(w, cs1[py], acc[py * P_ + px]);
                }
            }
        }
    }

    // ---- epilogue: live-px coalesced wave-atomics into outS ----
    float* os = outs + ((size_t)b * N_ + n) * (49 * C_) + c;
#pragma unroll
    for (int px = 0; px < P_; ++px) {
        if (live & (1 << px)) {
#pragma unroll
            for (int py = 0; py < P_; ++py)
                atomicAdd(os + (py * P_ + px) * C_, acc[py * P_ + px]);
        }
    }
}

// ---------------------------------------------------------------------------
// k_final: outS [b][n][py][px][c] -> out [b][n][c][py][px] via padded LDS.
__global__ __launch_bounds__(256) void k_final(const float* __restrict__ outs,
                                               float* __restrict__ out) {
    __shared__ float t[49 * 257];        // pad 257: conflict-free transpose read
    int bn  = blockIdx.x;                // 0..B*N-1
    int tid = (int)threadIdx.x;
    const float* src = outs + (size_t)bn * (49 * C_);
    for (int e = tid; e < 49 * C_; e += 256) {
        int q = e >> 8, c = e & 255;
        t[q * 257 + c] = src[e];         // coalesced read
    }
    __syncthreads();
    float* dst = out + (size_t)bn * (C_ * 49);
    for (int e = tid; e < C_ * 49; e += 256) {
        int c = e / 49, q = e % 49;
        dst[e] = t[q * 257 + c];         // coalesced write
    }
}

// ---------------------------------------------------------------------------
extern "C" void kernel_launch(void* const* d_in, const int* in_sizes, int n_in,
                              void* d_out, int out_size, void* d_ws, size_t ws_size,
                              hipStream_t stream) {
    const float* fm    = (const float*)d_in[0];
    const float* boxes = (const float*)d_in[1];
    const float* gt    = (const float*)d_in[2];
    float* ws_f = (float*)d_ws;
    float* out  = (float*)d_out;
    float* outs = ws_f + F_OUTS;

    k_prep<<<PREP_N, 256, 0, stream>>>(fm, boxes, gt, ws_f);
    k_main<<<B_ * N_ * JPN_, 256, 0, stream>>>(ws_f, outs);
    k_final<<<B_ * N_, 256, 0, stream>>>(outs, out);
}

// Round 11
// 169.613 us; speedup vs baseline: 1.1795x; 1.0685x over previous
//
#include <hip/hip_runtime.h>

#define B_ 2
#define C_ 256
#define H_ 56
#define W_ 56
#define N_ 64
#define M_ 8
#define P_ 7
#define R_ (N_ + N_*M_)          // 576 rois per image
#define BR_ (B_*R_)              // 1152
#define Y2_ (H_/2)               // 28 y-row pairs
#define SCTX_ 4                  // column chunks per ctx roi (box roi = whole)
#define JPN_ (1 + (M_)*SCTX_)    // 33 jobs per (b,n) -> 4224 blocks (R6-proven)
#define WROW_ 8                  // padded weight-row stride (7 used + col7 = 0)

typedef _Float16 half2v __attribute__((ext_vector_type(2)));

#if __has_builtin(__builtin_amdgcn_fdot2)
#define FDOT2(a, b, c) __builtin_amdgcn_fdot2((a), (b), (c), false)
#else
static __device__ __forceinline__ float FDOT2(half2v a, half2v b, float c) {
    return fmaf((float)a.x, (float)b.x, fmaf((float)a.y, (float)b.y, c));
}
#endif

// ---- workspace layout (dword-element offsets) ----
#define F_FMT3 0
#define N_FMT3 (B_*Y2_*W_*C_)                // 802,816  f16 y-pair-packed fmap [b][y2][x][c]
#define F_WY2  (F_FMT3 + N_FMT3)
#define N_WY2  (BR_*Y2_*WROW_)               // 258,048  half2 y-weights [y2][py], col7=0
#define F_AXD  (F_WY2 + N_WY2)
#define N_AXD  (BR_*W_*WROW_)                // 516,096  fp32 x-weights [x][px] (ctx /M), col7=0
#define F_WYF  (F_AXD + N_AXD)
#define N_WYF  (BR_*H_*WROW_)                // 516,096  fp32 y-weight scratch [y][p]
#define F_OUTS (F_WYF + N_WYF)
#define N_OUTS (B_*N_*49*C_)                 // 1,605,632 staging out [b][n][py][px][c]
#define E_XLO  (F_OUTS + N_OUTS)             // int region
#define E_XHI  (E_XLO + BR_)
#define E_YLO  (E_XHI + BR_)
#define E_YHI  (E_YLO + BR_)
#define WS_ELEMS (E_YHI + BR_)               // ~14.8 MB

// fused prep kernel block ranges
#define PREP_T (B_*Y2_*2)                    // 112: f16 pack-transpose (x-halves)
#define PREP_W (PREP_T + 32)                 // weights: 8192 threads
#define PREP_N (PREP_W + 784)                // zero outS: 784*2048 floats

// ---------------------------------------------------------------------------
// k_prep: three jobs in one dispatch.
//   [0,112):   fm[b][c][y][x] -> fmt3[b][y2][x][c] packed half2(rows 2y2,2y2+1)
//   [112,144): per-(br,p) dense axis weights. y: fp32 accumulate into GLOBAL
//              scratch column (no dynamic private arrays -> no scratch spill),
//              then pack half2 into wy2. x: direct fp32 column (R9-proven).
//   [144,928): zero outS
__global__ __launch_bounds__(256) void k_prep(const float* __restrict__ fm,
                                              const float* __restrict__ boxes,
                                              const float* __restrict__ gt,
                                              float* __restrict__ ws_f) {
    int bid = blockIdx.x;
    int tid = (int)threadIdx.x;

    if (bid < PREP_T) {                      // ---- pack-transpose ----
        int xh = bid & 1;
        int y2 = (bid >> 1) % Y2_;
        int b  = bid / (2 * Y2_);
        int c  = tid;                        // all 256 channels
        int x0 = xh * (W_ / 2);
        const float4* r0 = (const float4*)(fm + (((size_t)b * C_ + c) * H_ + 2 * y2) * W_ + x0);
        const float4* r1 = (const float4*)(fm + (((size_t)b * C_ + c) * H_ + 2 * y2 + 1) * W_ + x0);
        unsigned int* dst = (unsigned int*)ws_f + F_FMT3 +
                            (((size_t)b * Y2_ + y2) * W_ + x0) * (size_t)C_ + c;
#pragma unroll
        for (int x4 = 0; x4 < W_ / 8; ++x4) {   // 7 float4 = 28 columns
            float4 a = r0[x4];
            float4 bb = r1[x4];
            half2v h0; h0.x = (_Float16)a.x; h0.y = (_Float16)bb.x;
            half2v h1; h1.x = (_Float16)a.y; h1.y = (_Float16)bb.y;
            half2v h2; h2.x = (_Float16)a.z; h2.y = (_Float16)bb.z;
            half2v h3; h3.x = (_Float16)a.w; h3.y = (_Float16)bb.w;
            dst[(x4 * 4 + 0) * C_] = __builtin_bit_cast(unsigned int, h0);
            dst[(x4 * 4 + 1) * C_] = __builtin_bit_cast(unsigned int, h1);
            dst[(x4 * 4 + 2) * C_] = __builtin_bit_cast(unsigned int, h2);
            dst[(x4 * 4 + 3) * C_] = __builtin_bit_cast(unsigned int, h3);
        }
        return;
    }

    if (bid < PREP_W) {                      // ---- weights ----
        int t = (bid - PREP_T) * 256 + tid;
        if (t >= BR_ * P_) return;
        int p  = t % P_;
        int br = t / P_;
        int r  = br % R_;
        int b  = br / R_;
        int* ip = (int*)ws_f;

        float x1, y1, x2, y2;
        if (r < N_) {
            const float* bp = boxes + ((size_t)b * N_ + r) * 4;
            x1 = bp[0]; y1 = bp[1]; x2 = bp[2]; y2 = bp[3];
        } else {
            int q = r - N_;
            int n = q / M_, m = q % M_;
            const float* bp = boxes + ((size_t)b * N_ + n) * 4;
            const float* gp = gt + ((size_t)b * M_ + m) * 4;
            x1 = fminf(bp[0], gp[0]); y1 = fminf(bp[1], gp[1]);
            x2 = fmaxf(bp[2], gp[2]); y2 = fmaxf(bp[3], gp[3]);
        }
        float rw = fmaxf(x2 - x1, 1.0f);
        float rh = fmaxf(y2 - y1, 1.0f);

        {   // y axis: fp32 global scratch column, then pack half2 pairs
            float* wcol = ws_f + F_WYF + (size_t)br * (H_ * WROW_) + p;
            for (int y = 0; y < H_; ++y) wcol[y * WROW_] = 0.0f;
            float bin = rh / 7.0f;
            float gf  = ceilf(bin);
            int   g   = (int)gf;
            float ivg = 1.0f / gf;
            float start = y1 + (float)p * bin;
            for (int s = 0; s < g; ++s) {
                float coord = start + ((float)s + 0.5f) * bin * ivg;
                if (coord < -1.0f || coord > (float)H_) continue;
                float cc = fmaxf(coord, 0.0f);
                int low = (int)floorf(cc);
                int high; float l;
                if (low >= H_ - 1) { low = H_ - 1; high = H_ - 1; l = 0.0f; }
                else               { high = low + 1; l = cc - (float)low; }
                wcol[low  * WROW_] += (1.0f - l) * ivg;
                wcol[high * WROW_] += l * ivg;
            }
            unsigned int* wrow = (unsigned int*)ws_f + F_WY2 + (size_t)br * (Y2_ * WROW_);
            for (int q2 = 0; q2 < Y2_; ++q2) {
                half2v h;
                h.x = (_Float16)wcol[(2 * q2) * WROW_];
                h.y = (_Float16)wcol[(2 * q2 + 1) * WROW_];
                wrow[q2 * WROW_ + p] = __builtin_bit_cast(unsigned int, h);
                if (p == 0) wrow[q2 * WROW_ + 7] = 0u;   // pad col
            }
        }
        {   // x axis: direct fp32 column, ctx 1/M folded in
            float* acol = ws_f + F_AXD + (size_t)br * (W_ * WROW_) + p;
            for (int x = 0; x < W_; ++x) acol[x * WROW_] = 0.0f;
            if (p == 0) {
                float* pc = ws_f + F_AXD + (size_t)br * (W_ * WROW_) + 7;
                for (int x = 0; x < W_; ++x) pc[x * WROW_] = 0.0f;
            }
            float bin = rw / 7.0f;
            float gf  = ceilf(bin);
            int   g   = (int)gf;
            float ivg = 1.0f / gf;
            float fs  = (r < N_) ? ivg : ivg * (1.0f / (float)M_);
            float start = x1 + (float)p * bin;
            for (int s = 0; s < g; ++s) {
                float coord = start + ((float)s + 0.5f) * bin * ivg;
                if (coord < -1.0f || coord > (float)W_) continue;
                float cc = fmaxf(coord, 0.0f);
                int low = (int)floorf(cc);
                int high; float l;
                if (low >= W_ - 1) { low = W_ - 1; high = W_ - 1; l = 0.0f; }
                else               { high = low + 1; l = cc - (float)low; }
                acol[low  * WROW_] += (1.0f - l) * fs;
                acol[high * WROW_] += l * fs;
            }
            if (p == 0) {
                ip[E_XLO + br] = min(max((int)floorf(fmaxf(x1, 0.0f)), 0), W_ - 1);
                ip[E_XHI + br] = min(max((int)floorf(x1 + rw) + 1, 0), W_ - 1) + 1;
                ip[E_YLO + br] = min(max((int)floorf(fmaxf(y1, 0.0f)), 0), H_ - 1);
                ip[E_YHI + br] = min(max((int)floorf(y1 + rh) + 1, 0), H_ - 1) + 1;
            }
        }
        return;
    }

    {                                        // ---- zero outS ----
        int t = (bid - PREP_W) * 256 + tid;  // < 200,704
        float4 z = {0.0f, 0.0f, 0.0f, 0.0f};
        float4* dst = (float4*)(ws_f + F_OUTS);
        dst[t * 2]     = z;
        dst[t * 2 + 1] = z;
    }
}

// ---------------------------------------------------------------------------
// k_main: block = (b, n, j) (R6-proven chunking: j=0 box whole, else ctx roi
// (j-1)/4, x-quarter (j-1)&3). 256 thr = 4 waves = 4 channel groups. Inner
// loop: x-QUAD x y-PAIR via v_dot2_f32_f16: per y2-iter 4 independent data
// dwords + 2 wave-uniform dwordx4 weight loads feed 28 dot2 (= 56 FMAs),
// fp32 accumulation. Registers cs[4][7]+acc[49]+misc ~= 109 < 128 cap of
// (256,4). Epilogue: live-px coalesced atomics into outS [py][px][c].
__global__ __launch_bounds__(256, 4) void k_main(const float* __restrict__ ws_f,
                                                 float* __restrict__ outs) {
    const int* ip = (const int*)ws_f;
    int bid = blockIdx.x;
    int j   = bid % JPN_;
    int n   = (bid / JPN_) & (N_ - 1);
    int b   = bid / (JPN_ * N_);
    int k, s;
    if (j == 0) { k = 0; s = 0; }
    else        { k = 1 + ((j - 1) >> 2); s = (j - 1) & 3; }
    int tid  = (int)threadIdx.x;
    int lane = tid & 63;
    int rg   = tid >> 6;
    int c    = rg * 64 + lane;

    int r  = (k == 0) ? n : (N_ + n * M_ + (k - 1));
    int br = b * R_ + r;

    int xlo = ip[E_XLO + br];
    int xhi = ip[E_XHI + br];
    int ylo = ip[E_YLO + br];
    int yhi = ip[E_YHI + br];
    int xs, xe;
    if (k == 0) { xs = xlo; xe = xhi; }
    else {
        int cw = (xhi - xlo + SCTX_ - 1) >> 2;
        xs = xlo + s * cw;
        xe = min(xs + cw, xhi);
    }
    if (xs >= xe) return;                    // no barriers in kernel -> safe

    int ylo2 = ylo >> 1;                     // pair range covering [ylo,yhi)
    int yhi2 = (yhi + 1) >> 1;               // extra rows have zero weight

    const unsigned int* wy2 = (const unsigned int*)ws_f + F_WY2 + (size_t)br * (Y2_ * WROW_);
    const float*        axd = ws_f + F_AXD + (size_t)br * (W_ * WROW_);
    const unsigned int* f3  = (const unsigned int*)ws_f + F_FMT3 + (size_t)b * (Y2_ * W_ * C_);

    float acc[49];
#pragma unroll
    for (int q = 0; q < 49; ++q) acc[q] = 0.0f;
    int live = 0;

    for (int x = xs; x < xe; x += 4) {
        float cs[4][P_];
#pragma unroll
        for (int i = 0; i < 4; ++i)
#pragma unroll
            for (int py = 0; py < P_; ++py) cs[i][py] = 0.0f;

        // x+1..x+3 over-read past xe/roi edge is harmless: stays inside d_ws
        // (worst case spills into F_WY2 region), garbage columns never enter
        // acc (x-stage gated on xe).
        const unsigned int* col = f3 + ((size_t)(ylo2 * W_ + x)) * C_ + c;
        for (int y2 = ylo2; y2 < yhi2; ++y2) {
            unsigned int d0 = col[0];
            unsigned int d1 = col[C_];
            unsigned int d2 = col[2 * C_];
            unsigned int d3 = col[3 * C_];
            const uint4* wr = (const uint4*)(wy2 + y2 * WROW_);
            uint4 wa = wr[0];
            uint4 wb = wr[1];
            half2v v0 = __builtin_bit_cast(half2v, d0);
            half2v v1 = __builtin_bit_cast(half2v, d1);
            half2v v2 = __builtin_bit_cast(half2v, d2);
            half2v v3 = __builtin_bit_cast(half2v, d3);
            half2v w[7];
            w[0] = __builtin_bit_cast(half2v, wa.x);
            w[1] = __builtin_bit_cast(half2v, wa.y);
            w[2] = __builtin_bit_cast(half2v, wa.z);
            w[3] = __builtin_bit_cast(half2v, wa.w);
            w[4] = __builtin_bit_cast(half2v, wb.x);
            w[5] = __builtin_bit_cast(half2v, wb.y);
            w[6] = __builtin_bit_cast(half2v, wb.z);
#pragma unroll
            for (int py = 0; py < P_; ++py) {
                cs[0][py] = FDOT2(w[py], v0, cs[0][py]);
                cs[1][py] = FDOT2(w[py], v1, cs[1][py]);
                cs[2][py] = FDOT2(w[py], v2, cs[2][py]);
                cs[3][py] = FDOT2(w[py], v3, cs[3][py]);
            }
            col += W_ * C_;
        }

        // ---- x-stage (fp32, exact weights) ----
#pragma unroll
        for (int i = 0; i < 4; ++i) {
            if (x + i < xe) {                         // wave-uniform branch
                float av[8];
                *(float4*)(&av[0]) = *(const float4*)(axd + (x + i) * WROW_);
                *(float4*)(&av[4]) = *(const float4*)(axd + (x + i) * WROW_ + 4);
#pragma unroll
                for (int px = 0; px < P_; ++px) {
                    float w = av[px];
                    if (w != 0.0f) {
                        live |= 1 << px;
#pragma unroll
                        for (int py = 0; py < P_; ++py)
                            acc[py * P_ + px] = fmaf(w, cs[i][py], acc[py * P_ + px]);
                    }
                }
            }
        }
    }

    // ---- epilogue: live-px coalesced wave-atomics into outS ----
    float* os = outs + ((size_t)b * N_ + n) * (49 * C_) + c;
#pragma unroll
    for (int px = 0; px < P_; ++px) {
        if (live & (1 << px)) {
#pragma unroll
            for (int py = 0; py < P_; ++py)
                atomicAdd(os + (py * P_ + px) * C_, acc[py * P_ + px]);
        }
    }
}

// ---------------------------------------------------------------------------
// k_final: outS [b][n][py][px][c] -> out [b][n][c][py][px] via padded LDS.
__global__ __launch_bounds__(256) void k_final(const float* __restrict__ outs,
                                               float* __restrict__ out) {
    __shared__ float t[49 * 257];        // pad 257: conflict-free transpose read
    int bn  = blockIdx.x;                // 0..B*N-1
    int tid = (int)threadIdx.x;
    const float* src = outs + (size_t)bn * (49 * C_);
    for (int e = tid; e < 49 * C_; e += 256) {
        int q = e >> 8, c = e & 255;
        t[q * 257 + c] = src[e];         // coalesced read
    }
    __syncthreads();
    float* dst = out + (size_t)bn * (C_ * 49);
    for (int e = tid; e < C_ * 49; e += 256) {
        int c = e / 49, q = e % 49;
        dst[e] = t[q * 257 + c];         // coalesced write
    }
}

// ---------------------------------------------------------------------------
extern "C" void kernel_launch(void* const* d_in, const int* in_sizes, int n_in,
                              void* d_out, int out_size, void* d_ws, size_t ws_size,
                              hipStream_t stream) {
    const float* fm    = (const float*)d_in[0];
    const float* boxes = (const float*)d_in[1];
    const float* gt    = (const float*)d_in[2];
    float* ws_f = (float*)d_ws;
    float* out  = (float*)d_out;
    float* outs = ws_f + F_OUTS;

    k_prep<<<PREP_N, 256, 0, stream>>>(fm, boxes, gt, ws_f);
    k_main<<<B_ * N_ * JPN_, 256, 0, stream>>>(ws_f, outs);
    k_final<<<B_ * N_, 256, 0, stream>>>(outs, out);
}

// Round 12
// 168.374 us; speedup vs baseline: 1.1881x; 1.0074x over previous
//
#include <hip/hip_runtime.h>

#define B_ 2
#define C_ 256
#define H_ 56
#define W_ 56
#define N_ 64
#define M_ 8
#define P_ 7
#define R_ (N_ + N_*M_)          // 576 rois per image
#define BR_ (B_*R_)              // 1152
#define Y2_ (H_/2)               // 28 y-row pairs
#define SCTX_ 4                  // column chunks per ctx roi (box roi = whole)
#define JPN_ (1 + (M_)*SCTX_)    // 33 jobs per (b,n) -> 4224 blocks (R6-proven)
#define WROW_ 8                  // padded weight-row stride (7 used + col7 = 0)
#define WYFS_ 8192               // wyf scratch stride: [y][thread] coalesced

typedef _Float16 half2v __attribute__((ext_vector_type(2)));

#if __has_builtin(__builtin_amdgcn_fdot2)
#define FDOT2(a, b, c) __builtin_amdgcn_fdot2((a), (b), (c), false)
#else
static __device__ __forceinline__ float FDOT2(half2v a, half2v b, float c) {
    return fmaf((float)a.x, (float)b.x, fmaf((float)a.y, (float)b.y, c));
}
#endif

// ---- workspace layout (dword-element offsets) ----
#define F_FMT3 0
#define N_FMT3 (B_*Y2_*W_*C_)                // 802,816  f16 y-pair-packed fmap [b][y2][x][c]
#define F_WY2  (F_FMT3 + N_FMT3)
#define N_WY2  (BR_*Y2_*WROW_)               // 258,048  half2 y-weights [y2][py], col7=0
#define F_AXD  (F_WY2 + N_WY2)
#define N_AXD  (BR_*W_*WROW_)                // 516,096  fp32 x-weights [x][px] (ctx /M), col7=0
#define F_WYF  (F_AXD + N_AXD)
#define N_WYF  (H_*WYFS_)                    // 458,752  fp32 y-scratch [y][thread] (coalesced)
#define F_OUTS (F_WYF + N_WYF)
#define N_OUTS (B_*N_*49*C_)                 // 1,605,632 staging out [b][n][py][px][c]
#define E_XLO  (F_OUTS + N_OUTS)             // int region
#define E_XHI  (E_XLO + BR_)
#define E_YLO  (E_XHI + BR_)
#define E_YHI  (E_YLO + BR_)
#define WS_ELEMS (E_YHI + BR_)               // ~14.6 MB

// fused prep kernel block ranges
#define PREP_T (B_*Y2_*2)                    // 112: f16 pack-transpose (x-halves)
#define PREP_W (PREP_T + 32)                 // weights: 8192 threads
#define PREP_N (PREP_W + 784)                // zero outS: 784*2048 floats

// ---------------------------------------------------------------------------
// k_prep: three jobs in one dispatch.
//   [0,112):   fm[b][c][y][x] -> fmt3[b][y2][x][c] packed half2(rows 2y2,2y2+1)
//   [112,144): per-(br,p) dense axis weights. y: fp32 accumulate into
//              [y][thread]-layout scratch (zero/pack fully coalesced), then
//              pack half2 into wy2. x: direct fp32 column (R6-proven cost).
//   [144,928): zero outS
__global__ __launch_bounds__(256) void k_prep(const float* __restrict__ fm,
                                              const float* __restrict__ boxes,
                                              const float* __restrict__ gt,
                                              float* __restrict__ ws_f) {
    int bid = blockIdx.x;
    int tid = (int)threadIdx.x;

    if (bid < PREP_T) {                      // ---- pack-transpose ----
        int xh = bid & 1;
        int y2 = (bid >> 1) % Y2_;
        int b  = bid / (2 * Y2_);
        int c  = tid;                        // all 256 channels
        int x0 = xh * (W_ / 2);
        const float4* r0 = (const float4*)(fm + (((size_t)b * C_ + c) * H_ + 2 * y2) * W_ + x0);
        const float4* r1 = (const float4*)(fm + (((size_t)b * C_ + c) * H_ + 2 * y2 + 1) * W_ + x0);
        unsigned int* dst = (unsigned int*)ws_f + F_FMT3 +
                            (((size_t)b * Y2_ + y2) * W_ + x0) * (size_t)C_ + c;
#pragma unroll
        for (int x4 = 0; x4 < W_ / 8; ++x4) {   // 7 float4 = 28 columns
            float4 a = r0[x4];
            float4 bb = r1[x4];
            half2v h0; h0.x = (_Float16)a.x; h0.y = (_Float16)bb.x;
            half2v h1; h1.x = (_Float16)a.y; h1.y = (_Float16)bb.y;
            half2v h2; h2.x = (_Float16)a.z; h2.y = (_Float16)bb.z;
            half2v h3; h3.x = (_Float16)a.w; h3.y = (_Float16)bb.w;
            dst[(x4 * 4 + 0) * C_] = __builtin_bit_cast(unsigned int, h0);
            dst[(x4 * 4 + 1) * C_] = __builtin_bit_cast(unsigned int, h1);
            dst[(x4 * 4 + 2) * C_] = __builtin_bit_cast(unsigned int, h2);
            dst[(x4 * 4 + 3) * C_] = __builtin_bit_cast(unsigned int, h3);
        }
        return;
    }

    if (bid < PREP_W) {                      // ---- weights ----
        int t = (bid - PREP_T) * 256 + tid;
        if (t >= BR_ * P_) return;
        int p  = t % P_;
        int br = t / P_;
        int r  = br % R_;
        int b  = br / R_;
        int* ip = (int*)ws_f;

        float x1, y1, x2, y2;
        if (r < N_) {
            const float* bp = boxes + ((size_t)b * N_ + r) * 4;
            x1 = bp[0]; y1 = bp[1]; x2 = bp[2]; y2 = bp[3];
        } else {
            int q = r - N_;
            int n = q / M_, m = q % M_;
            const float* bp = boxes + ((size_t)b * N_ + n) * 4;
            const float* gp = gt + ((size_t)b * M_ + m) * 4;
            x1 = fminf(bp[0], gp[0]); y1 = fminf(bp[1], gp[1]);
            x2 = fmaxf(bp[2], gp[2]); y2 = fmaxf(bp[3], gp[3]);
        }
        float rw = fmaxf(x2 - x1, 1.0f);
        float rh = fmaxf(y2 - y1, 1.0f);

        {   // y axis: [y][thread] scratch — zero & pack coalesced
            float* wcol = ws_f + F_WYF + t;
            for (int y = 0; y < H_; ++y) wcol[y * WYFS_] = 0.0f;
            float bin = rh / 7.0f;
            float gf  = ceilf(bin);
            int   g   = (int)gf;
            float ivg = 1.0f / gf;
            float start = y1 + (float)p * bin;
            for (int s = 0; s < g; ++s) {
                float coord = start + ((float)s + 0.5f) * bin * ivg;
                if (coord < -1.0f || coord > (float)H_) continue;
                float cc = fmaxf(coord, 0.0f);
                int low = (int)floorf(cc);
                int high; float l;
                if (low >= H_ - 1) { low = H_ - 1; high = H_ - 1; l = 0.0f; }
                else               { high = low + 1; l = cc - (float)low; }
                wcol[low  * WYFS_] += (1.0f - l) * ivg;
                wcol[high * WYFS_] += l * ivg;
            }
            unsigned int* wrow = (unsigned int*)ws_f + F_WY2 + (size_t)br * (Y2_ * WROW_);
            for (int q2 = 0; q2 < Y2_; ++q2) {
                half2v h;
                h.x = (_Float16)wcol[(2 * q2) * WYFS_];
                h.y = (_Float16)wcol[(2 * q2 + 1) * WYFS_];
                wrow[q2 * WROW_ + p] = __builtin_bit_cast(unsigned int, h);
                if (p == 0) wrow[q2 * WROW_ + 7] = 0u;   // pad col
            }
        }
        {   // x axis: direct fp32 column, ctx 1/M folded in
            float* acol = ws_f + F_AXD + (size_t)br * (W_ * WROW_) + p;
            for (int x = 0; x < W_; ++x) acol[x * WROW_] = 0.0f;
            if (p == 0) {
                float* pc = ws_f + F_AXD + (size_t)br * (W_ * WROW_) + 7;
                for (int x = 0; x < W_; ++x) pc[x * WROW_] = 0.0f;
            }
            float bin = rw / 7.0f;
            float gf  = ceilf(bin);
            int   g   = (int)gf;
            float ivg = 1.0f / gf;
            float fs  = (r < N_) ? ivg : ivg * (1.0f / (float)M_);
            float start = x1 + (float)p * bin;
            for (int s = 0; s < g; ++s) {
                float coord = start + ((float)s + 0.5f) * bin * ivg;
                if (coord < -1.0f || coord > (float)W_) continue;
                float cc = fmaxf(coord, 0.0f);
                int low = (int)floorf(cc);
                int high; float l;
                if (low >= W_ - 1) { low = W_ - 1; high = W_ - 1; l = 0.0f; }
                else               { high = low + 1; l = cc - (float)low; }
                acol[low  * WROW_] += (1.0f - l) * fs;
                acol[high * WROW_] += l * fs;
            }
            if (p == 0) {
                ip[E_XLO + br] = min(max((int)floorf(fmaxf(x1, 0.0f)), 0), W_ - 1);
                ip[E_XHI + br] = min(max((int)floorf(x1 + rw) + 1, 0), W_ - 1) + 1;
                ip[E_YLO + br] = min(max((int)floorf(fmaxf(y1, 0.0f)), 0), H_ - 1);
                ip[E_YHI + br] = min(max((int)floorf(y1 + rh) + 1, 0), H_ - 1) + 1;
            }
        }
        return;
    }

    {                                        // ---- zero outS ----
        int t = (bid - PREP_W) * 256 + tid;  // < 200,704
        float4 z = {0.0f, 0.0f, 0.0f, 0.0f};
        float4* dst = (float4*)(ws_f + F_OUTS);
        dst[t * 2]     = z;
        dst[t * 2 + 1] = z;
    }
}

// ---------------------------------------------------------------------------
// k_main: block = (b, n, j) (R6-proven chunking). 256 thr = 4 waves = 4
// channel groups. Inner loop: x-QUAD x y-PAIR dot2, 2-DEEP SOFTWARE PIPELINE:
// iter top prefetches next y2's 4 data dwords + 2 weight uint4s; compute uses
// values loaded one iteration ago -> load-use distance = 1 full iter (~70 cyc
// issue) x 4 waves/SIMD covers L2 latency. One-row over-reads at roi end stay
// inside d_ws (values unused). Epilogue: live-px coalesced atomics into outS.
__global__ __launch_bounds__(256, 4) void k_main(const float* __restrict__ ws_f,
                                                 float* __restrict__ outs) {
    const int* ip = (const int*)ws_f;
    int bid = blockIdx.x;
    int j   = bid % JPN_;
    int n   = (bid / JPN_) & (N_ - 1);
    int b   = bid / (JPN_ * N_);
    int k, s;
    if (j == 0) { k = 0; s = 0; }
    else        { k = 1 + ((j - 1) >> 2); s = (j - 1) & 3; }
    int tid  = (int)threadIdx.x;
    int lane = tid & 63;
    int rg   = tid >> 6;
    int c    = rg * 64 + lane;

    int r  = (k == 0) ? n : (N_ + n * M_ + (k - 1));
    int br = b * R_ + r;

    int xlo = ip[E_XLO + br];
    int xhi = ip[E_XHI + br];
    int ylo = ip[E_YLO + br];
    int yhi = ip[E_YHI + br];
    int xs, xe;
    if (k == 0) { xs = xlo; xe = xhi; }
    else {
        int cw = (xhi - xlo + SCTX_ - 1) >> 2;
        xs = xlo + s * cw;
        xe = min(xs + cw, xhi);
    }
    if (xs >= xe) return;                    // no barriers in kernel -> safe

    int ylo2 = ylo >> 1;                     // pair range covering [ylo,yhi)
    int yhi2 = (yhi + 1) >> 1;               // extra rows have zero weight

    const unsigned int* wy2 = (const unsigned int*)ws_f + F_WY2 + (size_t)br * (Y2_ * WROW_);
    const float*        axd = ws_f + F_AXD + (size_t)br * (W_ * WROW_);
    const unsigned int* f3  = (const unsigned int*)ws_f + F_FMT3 + (size_t)b * (Y2_ * W_ * C_);

    float acc[49];
#pragma unroll
    for (int q = 0; q < 49; ++q) acc[q] = 0.0f;
    int live = 0;

    for (int x = xs; x < xe; x += 4) {
        float cs[4][P_];
#pragma unroll
        for (int i = 0; i < 4; ++i)
#pragma unroll
            for (int py = 0; py < P_; ++py) cs[i][py] = 0.0f;

        // x+1..x+3 / one-y2-row over-reads past roi edge are harmless: all
        // addresses stay inside d_ws; garbage never enters acc (gated on xe,
        // and over-read y-row values are multiplied only after the swap that
        // never happens — loop exits first).
        const unsigned int* col = f3 + ((size_t)(ylo2 * W_ + x)) * C_ + c;
        const uint4* wp = (const uint4*)(wy2 + ylo2 * WROW_);
        unsigned int d0 = col[0];
        unsigned int d1 = col[C_];
        unsigned int d2 = col[2 * C_];
        unsigned int d3 = col[3 * C_];
        uint4 wa = wp[0];
        uint4 wb = wp[1];
        for (int y2 = ylo2; y2 < yhi2; ++y2) {
            const unsigned int* nc = col + W_ * C_;
            unsigned int e0 = nc[0];                   // prefetch next iter
            unsigned int e1 = nc[C_];
            unsigned int e2 = nc[2 * C_];
            unsigned int e3 = nc[3 * C_];
            uint4 na = wp[2];
            uint4 nb = wp[3];

            half2v v0 = __builtin_bit_cast(half2v, d0);
            half2v v1 = __builtin_bit_cast(half2v, d1);
            half2v v2 = __builtin_bit_cast(half2v, d2);
            half2v v3 = __builtin_bit_cast(half2v, d3);
            half2v w[7];
            w[0] = __builtin_bit_cast(half2v, wa.x);
            w[1] = __builtin_bit_cast(half2v, wa.y);
            w[2] = __builtin_bit_cast(half2v, wa.z);
            w[3] = __builtin_bit_cast(half2v, wa.w);
            w[4] = __builtin_bit_cast(half2v, wb.x);
            w[5] = __builtin_bit_cast(half2v, wb.y);
            w[6] = __builtin_bit_cast(half2v, wb.z);
#pragma unroll
            for (int py = 0; py < P_; ++py) {
                cs[0][py] = FDOT2(w[py], v0, cs[0][py]);
                cs[1][py] = FDOT2(w[py], v1, cs[1][py]);
                cs[2][py] = FDOT2(w[py], v2, cs[2][py]);
                cs[3][py] = FDOT2(w[py], v3, cs[3][py]);
            }
            d0 = e0; d1 = e1; d2 = e2; d3 = e3;
            wa = na; wb = nb;
            col = nc; wp += 2;
        }

        // ---- x-stage (fp32, exact weights) ----
#pragma unroll
        for (int i = 0; i < 4; ++i) {
            if (x + i < xe) {                         // wave-uniform branch
                float av[8];
                *(float4*)(&av[0]) = *(const float4*)(axd + (x + i) * WROW_);
                *(float4*)(&av[4]) = *(const float4*)(axd + (x + i) * WROW_ + 4);
#pragma unroll
                for (int px = 0; px < P_; ++px) {
                    float w = av[px];
                    if (w != 0.0f) {
                        live |= 1 << px;
#pragma unroll
                        for (int py = 0; py < P_; ++py)
                            acc[py * P_ + px] = fmaf(w, cs[i][py], acc[py * P_ + px]);
                    }
                }
            }
        }
    }

    // ---- epilogue: live-px coalesced wave-atomics into outS ----
    float* os = outs + ((size_t)b * N_ + n) * (49 * C_) + c;
#pragma unroll
    for (int px = 0; px < P_; ++px) {
        if (live & (1 << px)) {
#pragma unroll
            for (int py = 0; py < P_; ++py)
                atomicAdd(os + (py * P_ + px) * C_, acc[py * P_ + px]);
        }
    }
}

// ---------------------------------------------------------------------------
// k_final: outS [b][n][py][px][c] -> out [b][n][c][py][px] via padded LDS.
__global__ __launch_bounds__(256) void k_final(const float* __restrict__ outs,
                                               float* __restrict__ out) {
    __shared__ float t[49 * 257];        // pad 257: conflict-free transpose read
    int bn  = blockIdx.x;                // 0..B*N-1
    int tid = (int)threadIdx.x;
    const float* src = outs + (size_t)bn * (49 * C_);
    for (int e = tid; e < 49 * C_; e += 256) {
        int q = e >> 8, c = e & 255;
        t[q * 257 + c] = src[e];         // coalesced read
    }
    __syncthreads();
    float* dst = out + (size_t)bn * (C_ * 49);
    for (int e = tid; e < C_ * 49; e += 256) {
        int c = e / 49, q = e % 49;
        dst[e] = t[q * 257 + c];         // coalesced write
    }
}

// ---------------------------------------------------------------------------
extern "C" void kernel_launch(void* const* d_in, const int* in_sizes, int n_in,
                              void* d_out, int out_size, void* d_ws, size_t ws_size,
                              hipStream_t stream) {
    const float* fm    = (const float*)d_in[0];
    const float* boxes = (const float*)d_in[1];
    const float* gt    = (const float*)d_in[2];
    float* ws_f = (float*)d_ws;
    float* out  = (float*)d_out;
    float* outs = ws_f + F_OUTS;

    k_prep<<<PREP_N, 256, 0, stream>>>(fm, boxes, gt, ws_f);
    k_main<<<B_ * N_ * JPN_, 256, 0, stream>>>(ws_f, outs);
    k_final<<<B_ * N_, 256, 0, stream>>>(outs, out);
}